// Round 4
// baseline (1029.375 us; speedup 1.0000x reference)
//
#include <hip/hip_runtime.h>
#include <hip/hip_bf16.h>

// Problem constants (fixed by the reference)
#define NN 150000      // nodes
#define EE 600000      // edges
#define F_IN 32        // input node features
#define HD 128         // hidden dim
#define GG 2048        // graphs
#define CAP 28         // max degree bucket capacity (Poisson(4): P(deg>=28) ~ 4e-18)
#define NP 150016      // NN rounded up to 128-node blocks: 1172*128

typedef __attribute__((ext_vector_type(8))) short bf16x8;
typedef __attribute__((ext_vector_type(4))) float f32x4;

__device__ inline void split_bf16(float v, unsigned short& hi, unsigned short& lo) {
    __hip_bfloat16 h = __float2bfloat16(v);
    float hv = __bfloat162float(h);
    __hip_bfloat16 l = __float2bfloat16(v - hv);
    hi = *reinterpret_cast<unsigned short*>(&h);
    lo = *reinterpret_cast<unsigned short*>(&l);
}
__device__ inline unsigned short bf16_hi(float v) {
    __hip_bfloat16 h = __float2bfloat16(v);
    return *reinterpret_cast<unsigned short*>(&h);
}
__device__ inline float bf2f(unsigned short u) {
    union { unsigned int i; float f; } c;
    c.i = ((unsigned int)u) << 16;
    return c.f;
}

// ---------------------------------------------------------------------------
// Zero-init for workspace regions
// ---------------------------------------------------------------------------
__global__ void init_zero(int* __restrict__ cnt_node, float* __restrict__ pooled) {
    int i = blockIdx.x * blockDim.x + threadIdx.x;
    if (i < NN) cnt_node[i] = 0;
    if (i < GG * HD) pooled[i] = 0.f;
}

// ---------------------------------------------------------------------------
// CSR-bucket build. AoS bucket[dst*CAP+slot].
// ---------------------------------------------------------------------------
__global__ void build_graph(const int* __restrict__ ei,
                            int* __restrict__ cnt_node,
                            int* __restrict__ bucket) {
    int e = blockIdx.x * blockDim.x + threadIdx.x;
    if (e >= EE) return;
    int src = ei[e];         // edge_index[0]
    int dst = ei[EE + e];    // edge_index[1]
    int slot = atomicAdd(&cnt_node[dst], 1);
    if (slot < CAP) bucket[dst * CAP + slot] = src;
}

// ---------------------------------------------------------------------------
// Weight prep: fp32 W[K][H] -> split-bf16 packed in LANE-LINEAR fragment order
// ---------------------------------------------------------------------------
struct PrepDesc { const float* src; unsigned short* dhi; unsigned short* dlo; int K; };
struct PrepArgs { PrepDesc d[9]; };

__global__ void prep_weights(PrepArgs pa) {
    PrepDesc de = pa.d[blockIdx.y];
    int total = de.K * HD;
    int KS = de.K >> 5;
    for (int idx = blockIdx.x * blockDim.x + threadIdx.x; idx < total;
         idx += gridDim.x * blockDim.x) {
        int k = idx / HD, h = idx - (idx / HD) * HD;   // src is [K][H]
        unsigned short hi, lo;
        split_bf16(de.src[idx], hi, lo);
        int nt = h >> 4, m = h & 15;
        int ks = k >> 5, quad = (k >> 3) & 3, e = k & 7;
        int lane = quad * 16 + m;
        int pidx = ((nt * KS + ks) * 64 + lane) * 8 + e;
        de.dhi[pidx] = hi;
        de.dlo[pidx] = lo;
    }
}

// ---------------------------------------------------------------------------
// Fused GIN layer (R4): gather-aggregate + 3-stage MFMA MLP.
//
// R4: latency/concurrency theory — the layer is bound by wave-level
// concurrency, capped by LDS (33792 B -> 4 blocks/CU, ~26% occupancy).
// Shrink the per-wave transpose buffer to EXACTLY [16][128] u32 with an
// XOR swizzle (word ^= (row&7)<<2) instead of +4 padding: 32768 B/block ->
// 5 blocks/CU (full 160 KiB pool), +25-67% resident waves. Swizzle keeps
// every b128/b64/b32 access 16B-contiguous and bank-parity with the old
// padded layout (2-way on writes).
// ---------------------------------------------------------------------------
template <int K_IN, bool BF16IN, bool POOL>
__launch_bounds__(256, 5)
__global__ void gin_layer(const void* __restrict__ hin_,
                          const int* __restrict__ cnt_node,
                          const int* __restrict__ bucket,
                          const unsigned short* __restrict__ w1h, const unsigned short* __restrict__ w1l,
                          const float* __restrict__ b1,
                          const unsigned short* __restrict__ w2h, const unsigned short* __restrict__ w2l,
                          const float* __restrict__ b2,
                          const unsigned short* __restrict__ w3h, const unsigned short* __restrict__ w3l,
                          const float* __restrict__ b3,
                          unsigned short* __restrict__ out,   // bf16 activations (non-pool)
                          const int* __restrict__ batch,
                          float* __restrict__ pooled) {
    constexpr int KS1 = K_IN / 32;
    constexpr int UN = BF16IN ? 4 : (KS1 == 1 ? 8 : 2);   // gather unroll depth
    // Per-wave swizzled transpose buffer: 16 rows x 128 u32 = 8192 B.
    // 4 waves x 8192 = 32768 B / block -> 5 blocks/CU.
    __shared__ unsigned int shp[4][16][128];

    const int wave = threadIdx.x >> 6;
    const int lane = threadIdx.x & 63;
    const int m = lane & 15;      // node row within a 16-set / out-feature col
    const int quad = lane >> 4;   // 0..3
    const int nodeBase = blockIdx.x * 128 + wave * 32;

    const float* hf = (const float*)hin_;
    const unsigned short* hb = (const unsigned short*)hin_;

    // ---- fused aggregation: self + neighbors, fp32 -> split-bf16 A frags ----
    bf16x8 ah[2][KS1], al[2][KS1];
#pragma unroll
    for (int s = 0; s < 2; s++) {
        int node = nodeBase + s * 16 + m;
        node = node < NN ? node : NN - 1;
        float ag[KS1][8];
        if (BF16IN) {
            const unsigned short* rs = hb + (size_t)node * K_IN + quad * 8;
#pragma unroll
            for (int ks = 0; ks < KS1; ks++) {
                bf16x8 v = *(const bf16x8*)(rs + ks * 32);
#pragma unroll
                for (int e = 0; e < 8; e++) ag[ks][e] = bf2f((unsigned short)v[e]);
            }
        } else {
            const float* rs = hf + (size_t)node * K_IN + quad * 8;
#pragma unroll
            for (int ks = 0; ks < KS1; ks++) {
                float4 v0 = *(const float4*)(rs + ks * 32);
                float4 v1 = *(const float4*)(rs + ks * 32 + 4);
                ag[ks][0] = v0.x; ag[ks][1] = v0.y; ag[ks][2] = v0.z; ag[ks][3] = v0.w;
                ag[ks][4] = v1.x; ag[ks][5] = v1.y; ag[ks][6] = v1.z; ag[ks][7] = v1.w;
            }
        }
        int cnt = cnt_node[node];
        cnt = cnt < CAP ? cnt : CAP;
        const int* b = bucket + (size_t)node * CAP;
        int i = 0;
        if (BF16IN) {
            for (; i + UN <= cnt; i += UN) {
                bf16x8 v[UN][KS1];
#pragma unroll
                for (int j = 0; j < UN; j++) {
                    const unsigned short* r = hb + (size_t)b[i + j] * K_IN + quad * 8;
#pragma unroll
                    for (int ks = 0; ks < KS1; ks++)
                        v[j][ks] = *(const bf16x8*)(r + ks * 32);
                }
#pragma unroll
                for (int ks = 0; ks < KS1; ks++)
#pragma unroll
                    for (int e = 0; e < 8; e++) {
                        float t01 = bf2f((unsigned short)v[0][ks][e]) +
                                    bf2f((unsigned short)v[1][ks][e]);
                        float t23 = bf2f((unsigned short)v[2][ks][e]) +
                                    bf2f((unsigned short)v[3][ks][e]);
                        ag[ks][e] += t01 + t23;
                    }
            }
            for (; i < cnt; i++) {
                const unsigned short* r = hb + (size_t)b[i] * K_IN + quad * 8;
#pragma unroll
                for (int ks = 0; ks < KS1; ks++) {
                    bf16x8 v = *(const bf16x8*)(r + ks * 32);
#pragma unroll
                    for (int e = 0; e < 8; e++) ag[ks][e] += bf2f((unsigned short)v[e]);
                }
            }
        } else {
            for (; i + UN <= cnt; i += UN) {
                float4 v0[UN][KS1], v1[UN][KS1];
#pragma unroll
                for (int j = 0; j < UN; j++) {
                    const float* r = hf + (size_t)b[i + j] * K_IN + quad * 8;
#pragma unroll
                    for (int ks = 0; ks < KS1; ks++) {
                        v0[j][ks] = *(const float4*)(r + ks * 32);
                        v1[j][ks] = *(const float4*)(r + ks * 32 + 4);
                    }
                }
#pragma unroll
                for (int ks = 0; ks < KS1; ks++) {
#pragma unroll
                    for (int e = 0; e < 4; e++) {
                        float s01 = (&v0[0][ks].x)[e] + (&v0[1][ks].x)[e];
                        float s23 = (&v0[2][ks].x)[e] + (&v0[3][ks].x)[e];
                        if (UN == 8) {
                            s01 += (&v0[4][ks].x)[e] + (&v0[5][ks].x)[e];
                            s23 += (&v0[6][ks].x)[e] + (&v0[7][ks].x)[e];
                        }
                        ag[ks][e] += s01 + s23;
                    }
#pragma unroll
                    for (int e = 0; e < 4; e++) {
                        float s01 = (&v1[0][ks].x)[e] + (&v1[1][ks].x)[e];
                        float s23 = (&v1[2][ks].x)[e] + (&v1[3][ks].x)[e];
                        if (UN == 8) {
                            s01 += (&v1[4][ks].x)[e] + (&v1[5][ks].x)[e];
                            s23 += (&v1[6][ks].x)[e] + (&v1[7][ks].x)[e];
                        }
                        ag[ks][e + 4] += s01 + s23;
                    }
                }
            }
            for (; i < cnt; i++) {
                const float* r = hf + (size_t)b[i] * K_IN + quad * 8;
#pragma unroll
                for (int ks = 0; ks < KS1; ks++) {
                    float4 v0 = *(const float4*)(r + ks * 32);
                    float4 v1 = *(const float4*)(r + ks * 32 + 4);
                    ag[ks][0] += v0.x; ag[ks][1] += v0.y; ag[ks][2] += v0.z; ag[ks][3] += v0.w;
                    ag[ks][4] += v1.x; ag[ks][5] += v1.y; ag[ks][6] += v1.z; ag[ks][7] += v1.w;
                }
            }
        }
#pragma unroll
        for (int ks = 0; ks < KS1; ks++) {
            bf16x8 vh, vl;
#pragma unroll
            for (int e = 0; e < 8; e++) {
                unsigned short hi, lo;
                split_bf16(ag[ks][e], hi, lo);
                vh[e] = (short)hi;
                vl[e] = (short)lo;
            }
            ah[s][ks] = vh;
            al[s][ks] = vl;
        }
    }

    f32x4 acc[2][8];

    // ---- stage 1 ----
#pragma unroll
    for (int nt = 0; nt < 8; nt++) {
        bf16x8 bh[KS1], bl[KS1];
#pragma unroll
        for (int ks = 0; ks < KS1; ks++) {
            bh[ks] = *(const bf16x8*)(w1h + ((nt * KS1 + ks) * 64 + lane) * 8);
            bl[ks] = *(const bf16x8*)(w1l + ((nt * KS1 + ks) * 64 + lane) * 8);
        }
        f32x4 c0 = {0.f, 0.f, 0.f, 0.f};
        f32x4 c1 = {0.f, 0.f, 0.f, 0.f};
#pragma unroll
        for (int ks = 0; ks < KS1; ks++) {
            c0 = __builtin_amdgcn_mfma_f32_16x16x32_bf16(ah[0][ks], bh[ks], c0, 0, 0, 0);
            c1 = __builtin_amdgcn_mfma_f32_16x16x32_bf16(ah[1][ks], bh[ks], c1, 0, 0, 0);
            c0 = __builtin_amdgcn_mfma_f32_16x16x32_bf16(al[0][ks], bh[ks], c0, 0, 0, 0);
            c1 = __builtin_amdgcn_mfma_f32_16x16x32_bf16(al[1][ks], bh[ks], c1, 0, 0, 0);
            c0 = __builtin_amdgcn_mfma_f32_16x16x32_bf16(ah[0][ks], bl[ks], c0, 0, 0, 0);
            c1 = __builtin_amdgcn_mfma_f32_16x16x32_bf16(ah[1][ks], bl[ks], c1, 0, 0, 0);
        }
        acc[0][nt] = c0;
        acc[1][nt] = c1;
    }

    // ---- transpose 1->2: packed u32 (hi|lo<<16), swizzled [16][128] ----
    bf16x8 a2h[2][4], a2l[2][4];
    const int fxm = (m & 7) << 2;          // read-side swizzle for row m
#pragma unroll
    for (int s = 0; s < 2; s++) {
#pragma unroll
        for (int nt = 0; nt < 8; nt++) {
            float bj = b1[nt * 16 + m];
#pragma unroll
            for (int r = 0; r < 4; r++) {
                unsigned short hi, lo;
                split_bf16(fmaxf(acc[s][nt][r] + bj, 0.f), hi, lo);
                int row = quad * 4 + r;
                shp[wave][row][(nt * 16 + m) ^ (((row & 7)) << 2)] =
                    (unsigned int)hi | ((unsigned int)lo << 16);
            }
        }
#pragma unroll
        for (int ks = 0; ks < 4; ks++) {
            const unsigned int* rowp = &shp[wave][m][0];
            int base = ks * 32 + quad * 8;
            uint4 wa = *(const uint4*)&rowp[base ^ fxm];
            uint4 wb = *(const uint4*)&rowp[(base + 4) ^ fxm];
            union { unsigned int u[4]; bf16x8 v; } ch, cl;
            ch.u[0] = __builtin_amdgcn_perm(wa.y, wa.x, 0x05040100u);
            ch.u[1] = __builtin_amdgcn_perm(wa.w, wa.z, 0x05040100u);
            ch.u[2] = __builtin_amdgcn_perm(wb.y, wb.x, 0x05040100u);
            ch.u[3] = __builtin_amdgcn_perm(wb.w, wb.z, 0x05040100u);
            cl.u[0] = __builtin_amdgcn_perm(wa.y, wa.x, 0x07060302u);
            cl.u[1] = __builtin_amdgcn_perm(wa.w, wa.z, 0x07060302u);
            cl.u[2] = __builtin_amdgcn_perm(wb.y, wb.x, 0x07060302u);
            cl.u[3] = __builtin_amdgcn_perm(wb.w, wb.z, 0x07060302u);
            a2h[s][ks] = ch.v;
            a2l[s][ks] = cl.v;
        }
    }

    // ---- stage 2 ----
#pragma unroll
    for (int nt = 0; nt < 8; nt++) {
        bf16x8 bh[4], bl[4];
#pragma unroll
        for (int ks = 0; ks < 4; ks++) {
            bh[ks] = *(const bf16x8*)(w2h + ((nt * 4 + ks) * 64 + lane) * 8);
            bl[ks] = *(const bf16x8*)(w2l + ((nt * 4 + ks) * 64 + lane) * 8);
        }
        f32x4 c0 = {0.f, 0.f, 0.f, 0.f};
        f32x4 c1 = {0.f, 0.f, 0.f, 0.f};
#pragma unroll
        for (int ks = 0; ks < 4; ks++) {
            c0 = __builtin_amdgcn_mfma_f32_16x16x32_bf16(a2h[0][ks], bh[ks], c0, 0, 0, 0);
            c1 = __builtin_amdgcn_mfma_f32_16x16x32_bf16(a2h[1][ks], bh[ks], c1, 0, 0, 0);
            c0 = __builtin_amdgcn_mfma_f32_16x16x32_bf16(a2l[0][ks], bh[ks], c0, 0, 0, 0);
            c1 = __builtin_amdgcn_mfma_f32_16x16x32_bf16(a2l[1][ks], bh[ks], c1, 0, 0, 0);
            c0 = __builtin_amdgcn_mfma_f32_16x16x32_bf16(a2h[0][ks], bl[ks], c0, 0, 0, 0);
            c1 = __builtin_amdgcn_mfma_f32_16x16x32_bf16(a2h[1][ks], bl[ks], c1, 0, 0, 0);
        }
        acc[0][nt] = c0;
        acc[1][nt] = c1;
    }

    // ---- transpose 2->3 (same swizzled scheme) ----
#pragma unroll
    for (int s = 0; s < 2; s++) {
#pragma unroll
        for (int nt = 0; nt < 8; nt++) {
            float bj = b2[nt * 16 + m];
#pragma unroll
            for (int r = 0; r < 4; r++) {
                unsigned short hi, lo;
                split_bf16(fmaxf(acc[s][nt][r] + bj, 0.f), hi, lo);
                int row = quad * 4 + r;
                shp[wave][row][(nt * 16 + m) ^ (((row & 7)) << 2)] =
                    (unsigned int)hi | ((unsigned int)lo << 16);
            }
        }
#pragma unroll
        for (int ks = 0; ks < 4; ks++) {
            const unsigned int* rowp = &shp[wave][m][0];
            int base = ks * 32 + quad * 8;
            uint4 wa = *(const uint4*)&rowp[base ^ fxm];
            uint4 wb = *(const uint4*)&rowp[(base + 4) ^ fxm];
            union { unsigned int u[4]; bf16x8 v; } ch, cl;
            ch.u[0] = __builtin_amdgcn_perm(wa.y, wa.x, 0x05040100u);
            ch.u[1] = __builtin_amdgcn_perm(wa.w, wa.z, 0x05040100u);
            ch.u[2] = __builtin_amdgcn_perm(wb.y, wb.x, 0x05040100u);
            ch.u[3] = __builtin_amdgcn_perm(wb.w, wb.z, 0x05040100u);
            cl.u[0] = __builtin_amdgcn_perm(wa.y, wa.x, 0x07060302u);
            cl.u[1] = __builtin_amdgcn_perm(wa.w, wa.z, 0x07060302u);
            cl.u[2] = __builtin_amdgcn_perm(wb.y, wb.x, 0x07060302u);
            cl.u[3] = __builtin_amdgcn_perm(wb.w, wb.z, 0x07060302u);
            a2h[s][ks] = ch.v;
            a2l[s][ks] = cl.v;
        }
    }

    // ---- stage 3 ----
#pragma unroll
    for (int nt = 0; nt < 8; nt++) {
        bf16x8 bh[4], bl[4];
#pragma unroll
        for (int ks = 0; ks < 4; ks++) {
            bh[ks] = *(const bf16x8*)(w3h + ((nt * 4 + ks) * 64 + lane) * 8);
            bl[ks] = *(const bf16x8*)(w3l + ((nt * 4 + ks) * 64 + lane) * 8);
        }
        f32x4 c0 = {0.f, 0.f, 0.f, 0.f};
        f32x4 c1 = {0.f, 0.f, 0.f, 0.f};
#pragma unroll
        for (int ks = 0; ks < 4; ks++) {
            c0 = __builtin_amdgcn_mfma_f32_16x16x32_bf16(a2h[0][ks], bh[ks], c0, 0, 0, 0);
            c1 = __builtin_amdgcn_mfma_f32_16x16x32_bf16(a2h[1][ks], bh[ks], c1, 0, 0, 0);
            c0 = __builtin_amdgcn_mfma_f32_16x16x32_bf16(a2l[0][ks], bh[ks], c0, 0, 0, 0);
            c1 = __builtin_amdgcn_mfma_f32_16x16x32_bf16(a2l[1][ks], bh[ks], c1, 0, 0, 0);
            c0 = __builtin_amdgcn_mfma_f32_16x16x32_bf16(a2h[0][ks], bl[ks], c0, 0, 0, 0);
            c1 = __builtin_amdgcn_mfma_f32_16x16x32_bf16(a2h[1][ks], bl[ks], c1, 0, 0, 0);
        }
        acc[0][nt] = c0;
        acc[1][nt] = c1;
    }

    if (POOL) {
        // ---- fused mean-pool epilogue: swizzled [16][128] f32 buffer ----
        float* shf = (float*)&shp[wave][0][0];
#pragma unroll
        for (int h = 0; h < 2; h++) {
#pragma unroll
            for (int nt = 0; nt < 8; nt++) {
                float bj = b3[nt * 16 + m];
#pragma unroll
                for (int r = 0; r < 4; r++) {
                    int row = quad * 4 + r;
                    shf[row * 128 + ((nt * 16 + m) ^ ((row & 7) << 2))] =
                        fmaxf(acc[h][nt][r] + bj, 0.f);
                }
            }
            int c0 = lane * 2;
            float run0 = 0.f, run1 = 0.f;
            int gp = -1;
            for (int rrow = 0; rrow < 16; rrow++) {
                int node = nodeBase + h * 16 + rrow;
                if (node >= NN) break;
                int g = batch[node];
                float2 xv = *(const float2*)&shf[rrow * 128 + (c0 ^ ((rrow & 7) << 2))];
                if (g != gp) {
                    if (gp >= 0) {
                        atomicAdd(&pooled[(size_t)gp * HD + c0 + 0], run0);
                        atomicAdd(&pooled[(size_t)gp * HD + c0 + 1], run1);
                    }
                    run0 = xv.x; run1 = xv.y; gp = g;
                } else {
                    run0 += xv.x; run1 += xv.y;
                }
            }
            if (gp >= 0) {
                atomicAdd(&pooled[(size_t)gp * HD + c0 + 0], run0);
                atomicAdd(&pooled[(size_t)gp * HD + c0 + 1], run1);
            }
        }
    } else {
        // ---- epilogue: bf16 restage through swizzled LDS, coalesced stores ----
        unsigned short* sh16 = (unsigned short*)&shp[wave][0][0];  // [16][256] hw
#pragma unroll
        for (int s = 0; s < 2; s++) {
#pragma unroll
            for (int nt = 0; nt < 8; nt++) {
                float bj = b3[nt * 16 + m];
#pragma unroll
                for (int r = 0; r < 4; r++) {
                    int row = quad * 4 + r;
                    int h = nt * 16 + m;                  // feature halfword idx
                    int w2 = (h >> 1) ^ ((row & 7) << 2); // swizzled word
                    sh16[row * 256 + w2 * 2 + (h & 1)] =
                        bf16_hi(fmaxf(acc[s][nt][r] + bj, 0.f));
                }
            }
#pragma unroll
            for (int io = 0; io < 4; io++) {
                int row16 = io * 4 + quad;
                int wbase = (m * 4) ^ ((row16 & 7) << 2);
                int n2 = nodeBase + s * 16 + row16;
                bf16x8 v = *(const bf16x8*)&sh16[row16 * 256 + wbase * 2];
                if (n2 < NN) *(bf16x8*)&out[(size_t)n2 * HD + m * 8] = v;
            }
        }
    }
}

// ---------------------------------------------------------------------------
// Classifier head: one block (128 threads) per graph.
// Graph node counts via binary search on the SORTED batch array.
// ---------------------------------------------------------------------------
__device__ inline int lb_batch(const int* __restrict__ batch, int key) {
    int lo = 0, hi = NN;
    while (lo < hi) {
        int mid = (lo + hi) >> 1;
        if (batch[mid] < key) lo = mid + 1; else hi = mid;
    }
    return lo;
}

__launch_bounds__(128)
__global__ void head(const float* __restrict__ pooled, const int* __restrict__ batch,
                     const float* __restrict__ fc0_w, const float* __restrict__ fc0_b,
                     const float* __restrict__ fc1_w, const float* __restrict__ fc1_b,
                     const float* __restrict__ out_w, const float* __restrict__ out_b,
                     float* __restrict__ out) {
    int g = blockIdx.x;
    int j = threadIdx.x;
    __shared__ float s0[HD];
    __shared__ float s1[HD];
    int c = lb_batch(batch, g + 1) - lb_batch(batch, g);
    float cf = (float)(c > 1 ? c : 1);
    s0[j] = pooled[(size_t)g * HD + j] / cf;
    __syncthreads();

    float acc = fc0_b[j];
    for (int k = 0; k < HD; k += 4) {
        float4 hv = *(const float4*)&s0[k];
        acc = fmaf(hv.x, fc0_w[(k + 0) * HD + j], acc);
        acc = fmaf(hv.y, fc0_w[(k + 1) * HD + j], acc);
        acc = fmaf(hv.z, fc0_w[(k + 2) * HD + j], acc);
        acc = fmaf(hv.w, fc0_w[(k + 3) * HD + j], acc);
    }
    s1[j] = fmaxf(acc, 0.0f);
    __syncthreads();

    acc = fc1_b[j];
    for (int k = 0; k < HD; k += 4) {
        float4 hv = *(const float4*)&s1[k];
        acc = fmaf(hv.x, fc1_w[(k + 0) * HD + j], acc);
        acc = fmaf(hv.y, fc1_w[(k + 1) * HD + j], acc);
        acc = fmaf(hv.z, fc1_w[(k + 2) * HD + j], acc);
        acc = fmaf(hv.w, fc1_w[(k + 3) * HD + j], acc);
    }
    float v = fmaxf(acc, 0.0f);

    float p0 = v * out_w[j * 2 + 0];
    float p1 = v * out_w[j * 2 + 1];
    __syncthreads();
    s0[j] = p0;
    s1[j] = p1;
    __syncthreads();
    for (int off = 64; off >= 1; off >>= 1) {
        if (j < off) {
            s0[j] += s0[j + off];
            s1[j] += s1[j + off];
        }
        __syncthreads();
    }
    if (j == 0) {
        out[(size_t)g * 2 + 0] = s0[0] + out_b[0];
        out[(size_t)g * 2 + 1] = s1[0] + out_b[1];
    }
}

// ---------------------------------------------------------------------------
extern "C" void kernel_launch(void* const* d_in, const int* in_sizes, int n_in,
                              void* d_out, int out_size, void* d_ws, size_t ws_size,
                              hipStream_t stream) {
    const float* x     = (const float*)d_in[0];
    const int*   ei    = (const int*)d_in[1];
    const int*   batch = (const int*)d_in[2];
    const float* cw[3][6];
    for (int i = 0; i < 3; i++)
        for (int k = 0; k < 6; k++) cw[i][k] = (const float*)d_in[3 + 6 * i + k];
    const float* fc0_w = (const float*)d_in[21];
    const float* fc0_b = (const float*)d_in[22];
    const float* fc1_w = (const float*)d_in[23];
    const float* fc1_b = (const float*)d_in[24];
    const float* out_w = (const float*)d_in[25];
    const float* out_b = (const float*)d_in[26];
    float* out = (float*)d_out;

    char* ws = (char*)d_ws;
    size_t off = 0;
    auto carve = [&](size_t bytes) {
        void* p = ws + off;
        off += (bytes + 255) & ~(size_t)255;
        return p;
    };
    // cnt_node and pooled contiguous (zeroed together by init_zero)
    int*   cnt_node = (int*)carve((size_t)NN * 4);
    float* pooled   = (float*)carve((size_t)GG * HD * 4);
    int*   bucket   = (int*)carve((size_t)NN * CAP * 4);
    unsigned short* hA = (unsigned short*)carve((size_t)NP * HD * 2);
    unsigned short* hB = (unsigned short*)carve((size_t)NP * HD * 2);
    unsigned short* wHi[9];
    unsigned short* wLo[9];
    int wK[9] = {F_IN, HD, HD, HD, HD, HD, HD, HD, HD};
    for (int i = 0; i < 9; i++) {
        wHi[i] = (unsigned short*)carve((size_t)wK[i] * HD * 2);
        wLo[i] = (unsigned short*)carve((size_t)wK[i] * HD * 2);
    }
    (void)ws_size;

    init_zero<<<(GG * HD + 255) / 256, 256, 0, stream>>>(cnt_node, pooled);
    build_graph<<<(EE + 255) / 256, 256, 0, stream>>>(ei, cnt_node, bucket);

    PrepArgs pa;
    for (int l = 0; l < 3; l++)
        for (int s = 0; s < 3; s++) {
            int i = l * 3 + s;
            pa.d[i].src = cw[l][2 * s];
            pa.d[i].dhi = wHi[i];
            pa.d[i].dlo = wLo[i];
            pa.d[i].K = wK[i];
        }
    prep_weights<<<dim3(16, 9), 256, 0, stream>>>(pa);

    const int blocks = NP / 128;  // 1172

    // ---- GIN layer 0 (K=32, fp32 in): x -> hA (bf16) ----
    gin_layer<F_IN, false, false><<<blocks, 256, 0, stream>>>(x, cnt_node, bucket,
        wHi[0], wLo[0], cw[0][1], wHi[1], wLo[1], cw[0][3], wHi[2], wLo[2], cw[0][5],
        hA, batch, pooled);
    // ---- GIN layer 1 (bf16 in): hA -> hB (bf16) ----
    gin_layer<HD, true, false><<<blocks, 256, 0, stream>>>(hA, cnt_node, bucket,
        wHi[3], wLo[3], cw[1][1], wHi[4], wLo[4], cw[1][3], wHi[5], wLo[5], cw[1][5],
        hB, batch, pooled);
    // ---- GIN layer 2 (bf16 in): hB -> pooled (fused mean-pool sum) ----
    gin_layer<HD, true, true><<<blocks, 256, 0, stream>>>(hB, cnt_node, bucket,
        wHi[6], wLo[6], cw[2][1], wHi[7], wLo[7], cw[2][3], wHi[8], wLo[8], cw[2][5],
        nullptr, batch, pooled);

    // ---- head ----
    head<<<GG, 128, 0, stream>>>(pooled, batch, fc0_w, fc0_b, fc1_w, fc1_b, out_w, out_b, out);
}

// Round 5
// 618.421 us; speedup vs baseline: 1.6645x; 1.6645x over previous
//
#include <hip/hip_runtime.h>
#include <hip/hip_bf16.h>

// Problem constants (fixed by the reference)
#define NN 150000      // nodes
#define EE 600000      // edges
#define F_IN 32        // input node features
#define HD 128         // hidden dim
#define GG 2048        // graphs
#define CAP 28         // max degree bucket capacity (Poisson(4): P(deg>=28) ~ 4e-18)
#define NP 150016      // NN rounded up: 4688 blocks * 32 nodes

typedef __attribute__((ext_vector_type(8))) short bf16x8;
typedef __attribute__((ext_vector_type(4))) float f32x4;

__device__ inline void split_bf16(float v, unsigned short& hi, unsigned short& lo) {
    __hip_bfloat16 h = __float2bfloat16(v);
    float hv = __bfloat162float(h);
    __hip_bfloat16 l = __float2bfloat16(v - hv);
    hi = *reinterpret_cast<unsigned short*>(&h);
    lo = *reinterpret_cast<unsigned short*>(&l);
}
__device__ inline unsigned short bf16_hi(float v) {
    __hip_bfloat16 h = __float2bfloat16(v);
    return *reinterpret_cast<unsigned short*>(&h);
}
__device__ inline float bf2f(unsigned short u) {
    union { unsigned int i; float f; } c;
    c.i = ((unsigned int)u) << 16;
    return c.f;
}

// ---------------------------------------------------------------------------
// Zero-init for workspace regions
// ---------------------------------------------------------------------------
__global__ void init_zero(int* __restrict__ cnt_node, float* __restrict__ pooled) {
    int i = blockIdx.x * blockDim.x + threadIdx.x;
    if (i < NN) cnt_node[i] = 0;
    if (i < GG * HD) pooled[i] = 0.f;
}

// ---------------------------------------------------------------------------
// CSR-bucket build. AoS bucket[dst*CAP+slot].
// ---------------------------------------------------------------------------
__global__ void build_graph(const int* __restrict__ ei,
                            int* __restrict__ cnt_node,
                            int* __restrict__ bucket) {
    int e = blockIdx.x * blockDim.x + threadIdx.x;
    if (e >= EE) return;
    int src = ei[e];         // edge_index[0]
    int dst = ei[EE + e];    // edge_index[1]
    int slot = atomicAdd(&cnt_node[dst], 1);
    if (slot < CAP) bucket[dst * CAP + slot] = src;
}

// ---------------------------------------------------------------------------
// Weight prep: fp32 W[K][H] -> split-bf16 packed in LANE-LINEAR fragment order
// ---------------------------------------------------------------------------
struct PrepDesc { const float* src; unsigned short* dhi; unsigned short* dlo; int K; };
struct PrepArgs { PrepDesc d[9]; };

__global__ void prep_weights(PrepArgs pa) {
    PrepDesc de = pa.d[blockIdx.y];
    int total = de.K * HD;
    int KS = de.K >> 5;
    for (int idx = blockIdx.x * blockDim.x + threadIdx.x; idx < total;
         idx += gridDim.x * blockDim.x) {
        int k = idx / HD, h = idx - (idx / HD) * HD;   // src is [K][H]
        unsigned short hi, lo;
        split_bf16(de.src[idx], hi, lo);
        int nt = h >> 4, m = h & 15;
        int ks = k >> 5, quad = (k >> 3) & 3, e = k & 7;
        int lane = quad * 16 + m;
        int pidx = ((nt * KS + ks) * 64 + lane) * 8 + e;
        de.dhi[pidx] = hi;
        de.dlo[pidx] = lo;
    }
}

// ---------------------------------------------------------------------------
// Fused GIN layer (R5): gather-aggregate + 3-stage MFMA MLP.
//
// R5: wave-concurrency theory. Total work was only 4688 waves = 18.3/CU —
// the grid itself capped resident concurrency while every pipe sat ~85%
// idle. Halve the per-wave tile to 16 nodes (s-dim removed): 9376 waves =
// 36.6/CU of work, 2-wave 128-thread blocks (32 nodes), 16 KB LDS/block ->
// ~20+ resident waves/CU and real oversubscription. Per-wave serial chain
// (gather rounds, MFMA chains, transpose) halves. Swizzled packed-u32
// transpose kept from R3/R4 (correctness-verified). launch_bounds(128,3)
// mirrors R3's known-good regalloc (~84 VGPR, no spills — R4's (256,5)
// clamped VGPR to 48 and spilled 433 MB to scratch).
// ---------------------------------------------------------------------------
template <int K_IN, bool BF16IN, bool POOL>
__launch_bounds__(128, 3)
__global__ void gin_layer(const void* __restrict__ hin_,
                          const int* __restrict__ cnt_node,
                          const int* __restrict__ bucket,
                          const unsigned short* __restrict__ w1h, const unsigned short* __restrict__ w1l,
                          const float* __restrict__ b1,
                          const unsigned short* __restrict__ w2h, const unsigned short* __restrict__ w2l,
                          const float* __restrict__ b2,
                          const unsigned short* __restrict__ w3h, const unsigned short* __restrict__ w3l,
                          const float* __restrict__ b3,
                          unsigned short* __restrict__ out,   // bf16 activations (non-pool)
                          const int* __restrict__ batch,
                          float* __restrict__ pooled) {
    constexpr int KS1 = K_IN / 32;
    constexpr int UN = BF16IN ? 4 : (KS1 == 1 ? 8 : 2);   // gather unroll depth
    // Per-wave swizzled transpose buffer: 16 rows x 128 u32 = 8 KB.
    // 2 waves x 8 KB = 16 KB / block.
    __shared__ unsigned int shp[2][16][128];

    const int wave = threadIdx.x >> 6;
    const int lane = threadIdx.x & 63;
    const int m = lane & 15;      // node row within the 16-set / out-feature col
    const int quad = lane >> 4;   // 0..3
    const int nodeBase = blockIdx.x * 32 + wave * 16;

    const float* hf = (const float*)hin_;
    const unsigned short* hb = (const unsigned short*)hin_;

    // ---- fused aggregation: self + neighbors, fp32 -> split-bf16 A frags ----
    bf16x8 ah[KS1], al[KS1];
    {
        int node = nodeBase + m;
        node = node < NN ? node : NN - 1;
        float ag[KS1][8];
        if (BF16IN) {
            const unsigned short* rs = hb + (size_t)node * K_IN + quad * 8;
#pragma unroll
            for (int ks = 0; ks < KS1; ks++) {
                bf16x8 v = *(const bf16x8*)(rs + ks * 32);
#pragma unroll
                for (int e = 0; e < 8; e++) ag[ks][e] = bf2f((unsigned short)v[e]);
            }
        } else {
            const float* rs = hf + (size_t)node * K_IN + quad * 8;
#pragma unroll
            for (int ks = 0; ks < KS1; ks++) {
                float4 v0 = *(const float4*)(rs + ks * 32);
                float4 v1 = *(const float4*)(rs + ks * 32 + 4);
                ag[ks][0] = v0.x; ag[ks][1] = v0.y; ag[ks][2] = v0.z; ag[ks][3] = v0.w;
                ag[ks][4] = v1.x; ag[ks][5] = v1.y; ag[ks][6] = v1.z; ag[ks][7] = v1.w;
            }
        }
        int cnt = cnt_node[node];
        cnt = cnt < CAP ? cnt : CAP;
        const int* b = bucket + (size_t)node * CAP;
        int i = 0;
        if (BF16IN) {
            for (; i + UN <= cnt; i += UN) {
                bf16x8 v[UN][KS1];
#pragma unroll
                for (int j = 0; j < UN; j++) {
                    const unsigned short* r = hb + (size_t)b[i + j] * K_IN + quad * 8;
#pragma unroll
                    for (int ks = 0; ks < KS1; ks++)
                        v[j][ks] = *(const bf16x8*)(r + ks * 32);
                }
#pragma unroll
                for (int ks = 0; ks < KS1; ks++)
#pragma unroll
                    for (int e = 0; e < 8; e++) {
                        float t01 = bf2f((unsigned short)v[0][ks][e]) +
                                    bf2f((unsigned short)v[1][ks][e]);
                        float t23 = bf2f((unsigned short)v[2][ks][e]) +
                                    bf2f((unsigned short)v[3][ks][e]);
                        ag[ks][e] += t01 + t23;
                    }
            }
            for (; i < cnt; i++) {
                const unsigned short* r = hb + (size_t)b[i] * K_IN + quad * 8;
#pragma unroll
                for (int ks = 0; ks < KS1; ks++) {
                    bf16x8 v = *(const bf16x8*)(r + ks * 32);
#pragma unroll
                    for (int e = 0; e < 8; e++) ag[ks][e] += bf2f((unsigned short)v[e]);
                }
            }
        } else {
            for (; i + UN <= cnt; i += UN) {
                float4 v0[UN][KS1], v1[UN][KS1];
#pragma unroll
                for (int j = 0; j < UN; j++) {
                    const float* r = hf + (size_t)b[i + j] * K_IN + quad * 8;
#pragma unroll
                    for (int ks = 0; ks < KS1; ks++) {
                        v0[j][ks] = *(const float4*)(r + ks * 32);
                        v1[j][ks] = *(const float4*)(r + ks * 32 + 4);
                    }
                }
#pragma unroll
                for (int ks = 0; ks < KS1; ks++) {
#pragma unroll
                    for (int e = 0; e < 4; e++) {
                        float s01 = (&v0[0][ks].x)[e] + (&v0[1][ks].x)[e];
                        float s23 = (&v0[2][ks].x)[e] + (&v0[3][ks].x)[e];
                        if (UN == 8) {
                            s01 += (&v0[4][ks].x)[e] + (&v0[5][ks].x)[e];
                            s23 += (&v0[6][ks].x)[e] + (&v0[7][ks].x)[e];
                        }
                        ag[ks][e] += s01 + s23;
                    }
#pragma unroll
                    for (int e = 0; e < 4; e++) {
                        float s01 = (&v1[0][ks].x)[e] + (&v1[1][ks].x)[e];
                        float s23 = (&v1[2][ks].x)[e] + (&v1[3][ks].x)[e];
                        if (UN == 8) {
                            s01 += (&v1[4][ks].x)[e] + (&v1[5][ks].x)[e];
                            s23 += (&v1[6][ks].x)[e] + (&v1[7][ks].x)[e];
                        }
                        ag[ks][e + 4] += s01 + s23;
                    }
                }
            }
            for (; i < cnt; i++) {
                const float* r = hf + (size_t)b[i] * K_IN + quad * 8;
#pragma unroll
                for (int ks = 0; ks < KS1; ks++) {
                    float4 v0 = *(const float4*)(r + ks * 32);
                    float4 v1 = *(const float4*)(r + ks * 32 + 4);
                    ag[ks][0] += v0.x; ag[ks][1] += v0.y; ag[ks][2] += v0.z; ag[ks][3] += v0.w;
                    ag[ks][4] += v1.x; ag[ks][5] += v1.y; ag[ks][6] += v1.z; ag[ks][7] += v1.w;
                }
            }
        }
#pragma unroll
        for (int ks = 0; ks < KS1; ks++) {
            bf16x8 vh, vl;
#pragma unroll
            for (int e = 0; e < 8; e++) {
                unsigned short hi, lo;
                split_bf16(ag[ks][e], hi, lo);
                vh[e] = (short)hi;
                vl[e] = (short)lo;
            }
            ah[ks] = vh;
            al[ks] = vl;
        }
    }

    f32x4 acc[8];

    // ---- stage 1 ----
#pragma unroll
    for (int nt = 0; nt < 8; nt++) {
        f32x4 c0 = {0.f, 0.f, 0.f, 0.f};
#pragma unroll
        for (int ks = 0; ks < KS1; ks++) {
            bf16x8 bh = *(const bf16x8*)(w1h + ((nt * KS1 + ks) * 64 + lane) * 8);
            bf16x8 bl = *(const bf16x8*)(w1l + ((nt * KS1 + ks) * 64 + lane) * 8);
            c0 = __builtin_amdgcn_mfma_f32_16x16x32_bf16(ah[ks], bh, c0, 0, 0, 0);
            c0 = __builtin_amdgcn_mfma_f32_16x16x32_bf16(al[ks], bh, c0, 0, 0, 0);
            c0 = __builtin_amdgcn_mfma_f32_16x16x32_bf16(ah[ks], bl, c0, 0, 0, 0);
        }
        acc[nt] = c0;
    }

    // ---- transpose 1->2: packed u32 (hi|lo<<16), swizzled [16][128] ----
    bf16x8 a2h[4], a2l[4];
    const int fxm = (m & 7) << 2;          // read-side swizzle for row m
#pragma unroll
    for (int nt = 0; nt < 8; nt++) {
        float bj = b1[nt * 16 + m];
#pragma unroll
        for (int r = 0; r < 4; r++) {
            unsigned short hi, lo;
            split_bf16(fmaxf(acc[nt][r] + bj, 0.f), hi, lo);
            int row = quad * 4 + r;
            shp[wave][row][(nt * 16 + m) ^ ((row & 7) << 2)] =
                (unsigned int)hi | ((unsigned int)lo << 16);
        }
    }
#pragma unroll
    for (int ks = 0; ks < 4; ks++) {
        const unsigned int* rowp = &shp[wave][m][0];
        int base = ks * 32 + quad * 8;
        uint4 wa = *(const uint4*)&rowp[base ^ fxm];
        uint4 wb = *(const uint4*)&rowp[(base + 4) ^ fxm];
        union { unsigned int u[4]; bf16x8 v; } ch, cl;
        ch.u[0] = __builtin_amdgcn_perm(wa.y, wa.x, 0x05040100u);
        ch.u[1] = __builtin_amdgcn_perm(wa.w, wa.z, 0x05040100u);
        ch.u[2] = __builtin_amdgcn_perm(wb.y, wb.x, 0x05040100u);
        ch.u[3] = __builtin_amdgcn_perm(wb.w, wb.z, 0x05040100u);
        cl.u[0] = __builtin_amdgcn_perm(wa.y, wa.x, 0x07060302u);
        cl.u[1] = __builtin_amdgcn_perm(wa.w, wa.z, 0x07060302u);
        cl.u[2] = __builtin_amdgcn_perm(wb.y, wb.x, 0x07060302u);
        cl.u[3] = __builtin_amdgcn_perm(wb.w, wb.z, 0x07060302u);
        a2h[ks] = ch.v;
        a2l[ks] = cl.v;
    }

    // ---- stage 2 ----
#pragma unroll
    for (int nt = 0; nt < 8; nt++) {
        f32x4 c0 = {0.f, 0.f, 0.f, 0.f};
#pragma unroll
        for (int ks = 0; ks < 4; ks++) {
            bf16x8 bh = *(const bf16x8*)(w2h + ((nt * 4 + ks) * 64 + lane) * 8);
            bf16x8 bl = *(const bf16x8*)(w2l + ((nt * 4 + ks) * 64 + lane) * 8);
            c0 = __builtin_amdgcn_mfma_f32_16x16x32_bf16(a2h[ks], bh, c0, 0, 0, 0);
            c0 = __builtin_amdgcn_mfma_f32_16x16x32_bf16(a2l[ks], bh, c0, 0, 0, 0);
            c0 = __builtin_amdgcn_mfma_f32_16x16x32_bf16(a2h[ks], bl, c0, 0, 0, 0);
        }
        acc[nt] = c0;
    }

    // ---- transpose 2->3 (same swizzled scheme) ----
#pragma unroll
    for (int nt = 0; nt < 8; nt++) {
        float bj = b2[nt * 16 + m];
#pragma unroll
        for (int r = 0; r < 4; r++) {
            unsigned short hi, lo;
            split_bf16(fmaxf(acc[nt][r] + bj, 0.f), hi, lo);
            int row = quad * 4 + r;
            shp[wave][row][(nt * 16 + m) ^ ((row & 7) << 2)] =
                (unsigned int)hi | ((unsigned int)lo << 16);
        }
    }
#pragma unroll
    for (int ks = 0; ks < 4; ks++) {
        const unsigned int* rowp = &shp[wave][m][0];
        int base = ks * 32 + quad * 8;
        uint4 wa = *(const uint4*)&rowp[base ^ fxm];
        uint4 wb = *(const uint4*)&rowp[(base + 4) ^ fxm];
        union { unsigned int u[4]; bf16x8 v; } ch, cl;
        ch.u[0] = __builtin_amdgcn_perm(wa.y, wa.x, 0x05040100u);
        ch.u[1] = __builtin_amdgcn_perm(wa.w, wa.z, 0x05040100u);
        ch.u[2] = __builtin_amdgcn_perm(wb.y, wb.x, 0x05040100u);
        ch.u[3] = __builtin_amdgcn_perm(wb.w, wb.z, 0x05040100u);
        cl.u[0] = __builtin_amdgcn_perm(wa.y, wa.x, 0x07060302u);
        cl.u[1] = __builtin_amdgcn_perm(wa.w, wa.z, 0x07060302u);
        cl.u[2] = __builtin_amdgcn_perm(wb.y, wb.x, 0x07060302u);
        cl.u[3] = __builtin_amdgcn_perm(wb.w, wb.z, 0x07060302u);
        a2h[ks] = ch.v;
        a2l[ks] = cl.v;
    }

    // ---- stage 3 ----
#pragma unroll
    for (int nt = 0; nt < 8; nt++) {
        f32x4 c0 = {0.f, 0.f, 0.f, 0.f};
#pragma unroll
        for (int ks = 0; ks < 4; ks++) {
            bf16x8 bh = *(const bf16x8*)(w3h + ((nt * 4 + ks) * 64 + lane) * 8);
            bf16x8 bl = *(const bf16x8*)(w3l + ((nt * 4 + ks) * 64 + lane) * 8);
            c0 = __builtin_amdgcn_mfma_f32_16x16x32_bf16(a2h[ks], bh, c0, 0, 0, 0);
            c0 = __builtin_amdgcn_mfma_f32_16x16x32_bf16(a2l[ks], bh, c0, 0, 0, 0);
            c0 = __builtin_amdgcn_mfma_f32_16x16x32_bf16(a2h[ks], bl, c0, 0, 0, 0);
        }
        acc[nt] = c0;
    }

    if (POOL) {
        // ---- fused mean-pool epilogue: swizzled [16][128] f32 buffer ----
        float* shf = (float*)&shp[wave][0][0];
#pragma unroll
        for (int nt = 0; nt < 8; nt++) {
            float bj = b3[nt * 16 + m];
#pragma unroll
            for (int r = 0; r < 4; r++) {
                int row = quad * 4 + r;
                shf[row * 128 + ((nt * 16 + m) ^ ((row & 7) << 2))] =
                    fmaxf(acc[nt][r] + bj, 0.f);
            }
        }
        int c0 = lane * 2;
        float run0 = 0.f, run1 = 0.f;
        int gp = -1;
        for (int rrow = 0; rrow < 16; rrow++) {
            int node = nodeBase + rrow;
            if (node >= NN) break;
            int g = batch[node];
            float2 xv = *(const float2*)&shf[rrow * 128 + (c0 ^ ((rrow & 7) << 2))];
            if (g != gp) {
                if (gp >= 0) {
                    atomicAdd(&pooled[(size_t)gp * HD + c0 + 0], run0);
                    atomicAdd(&pooled[(size_t)gp * HD + c0 + 1], run1);
                }
                run0 = xv.x; run1 = xv.y; gp = g;
            } else {
                run0 += xv.x; run1 += xv.y;
            }
        }
        if (gp >= 0) {
            atomicAdd(&pooled[(size_t)gp * HD + c0 + 0], run0);
            atomicAdd(&pooled[(size_t)gp * HD + c0 + 1], run1);
        }
    } else {
        // ---- epilogue: bf16 restage through swizzled LDS, coalesced stores ----
        unsigned short* sh16 = (unsigned short*)&shp[wave][0][0];  // [16][256] hw
#pragma unroll
        for (int nt = 0; nt < 8; nt++) {
            float bj = b3[nt * 16 + m];
#pragma unroll
            for (int r = 0; r < 4; r++) {
                int row = quad * 4 + r;
                int h = nt * 16 + m;                  // feature halfword idx
                int w2 = (h >> 1) ^ ((row & 7) << 2); // swizzled word
                sh16[row * 256 + w2 * 2 + (h & 1)] =
                    bf16_hi(fmaxf(acc[nt][r] + bj, 0.f));
            }
        }
#pragma unroll
        for (int io = 0; io < 4; io++) {
            int row16 = io * 4 + quad;
            int wbase = (m * 4) ^ ((row16 & 7) << 2);
            int n2 = nodeBase + row16;
            bf16x8 v = *(const bf16x8*)&sh16[row16 * 256 + wbase * 2];
            if (n2 < NN) *(bf16x8*)&out[(size_t)n2 * HD + m * 8] = v;
        }
    }
}

// ---------------------------------------------------------------------------
// Classifier head: one block (128 threads) per graph.
// Graph node counts via binary search on the SORTED batch array.
// ---------------------------------------------------------------------------
__device__ inline int lb_batch(const int* __restrict__ batch, int key) {
    int lo = 0, hi = NN;
    while (lo < hi) {
        int mid = (lo + hi) >> 1;
        if (batch[mid] < key) lo = mid + 1; else hi = mid;
    }
    return lo;
}

__launch_bounds__(128)
__global__ void head(const float* __restrict__ pooled, const int* __restrict__ batch,
                     const float* __restrict__ fc0_w, const float* __restrict__ fc0_b,
                     const float* __restrict__ fc1_w, const float* __restrict__ fc1_b,
                     const float* __restrict__ out_w, const float* __restrict__ out_b,
                     float* __restrict__ out) {
    int g = blockIdx.x;
    int j = threadIdx.x;
    __shared__ float s0[HD];
    __shared__ float s1[HD];
    int c = lb_batch(batch, g + 1) - lb_batch(batch, g);
    float cf = (float)(c > 1 ? c : 1);
    s0[j] = pooled[(size_t)g * HD + j] / cf;
    __syncthreads();

    float acc = fc0_b[j];
    for (int k = 0; k < HD; k += 4) {
        float4 hv = *(const float4*)&s0[k];
        acc = fmaf(hv.x, fc0_w[(k + 0) * HD + j], acc);
        acc = fmaf(hv.y, fc0_w[(k + 1) * HD + j], acc);
        acc = fmaf(hv.z, fc0_w[(k + 2) * HD + j], acc);
        acc = fmaf(hv.w, fc0_w[(k + 3) * HD + j], acc);
    }
    s1[j] = fmaxf(acc, 0.0f);
    __syncthreads();

    acc = fc1_b[j];
    for (int k = 0; k < HD; k += 4) {
        float4 hv = *(const float4*)&s1[k];
        acc = fmaf(hv.x, fc1_w[(k + 0) * HD + j], acc);
        acc = fmaf(hv.y, fc1_w[(k + 1) * HD + j], acc);
        acc = fmaf(hv.z, fc1_w[(k + 2) * HD + j], acc);
        acc = fmaf(hv.w, fc1_w[(k + 3) * HD + j], acc);
    }
    float v = fmaxf(acc, 0.0f);

    float p0 = v * out_w[j * 2 + 0];
    float p1 = v * out_w[j * 2 + 1];
    __syncthreads();
    s0[j] = p0;
    s1[j] = p1;
    __syncthreads();
    for (int off = 64; off >= 1; off >>= 1) {
        if (j < off) {
            s0[j] += s0[j + off];
            s1[j] += s1[j + off];
        }
        __syncthreads();
    }
    if (j == 0) {
        out[(size_t)g * 2 + 0] = s0[0] + out_b[0];
        out[(size_t)g * 2 + 1] = s1[0] + out_b[1];
    }
}

// ---------------------------------------------------------------------------
extern "C" void kernel_launch(void* const* d_in, const int* in_sizes, int n_in,
                              void* d_out, int out_size, void* d_ws, size_t ws_size,
                              hipStream_t stream) {
    const float* x     = (const float*)d_in[0];
    const int*   ei    = (const int*)d_in[1];
    const int*   batch = (const int*)d_in[2];
    const float* cw[3][6];
    for (int i = 0; i < 3; i++)
        for (int k = 0; k < 6; k++) cw[i][k] = (const float*)d_in[3 + 6 * i + k];
    const float* fc0_w = (const float*)d_in[21];
    const float* fc0_b = (const float*)d_in[22];
    const float* fc1_w = (const float*)d_in[23];
    const float* fc1_b = (const float*)d_in[24];
    const float* out_w = (const float*)d_in[25];
    const float* out_b = (const float*)d_in[26];
    float* out = (float*)d_out;

    char* ws = (char*)d_ws;
    size_t off = 0;
    auto carve = [&](size_t bytes) {
        void* p = ws + off;
        off += (bytes + 255) & ~(size_t)255;
        return p;
    };
    // cnt_node and pooled contiguous (zeroed together by init_zero)
    int*   cnt_node = (int*)carve((size_t)NN * 4);
    float* pooled   = (float*)carve((size_t)GG * HD * 4);
    int*   bucket   = (int*)carve((size_t)NN * CAP * 4);
    unsigned short* hA = (unsigned short*)carve((size_t)NP * HD * 2);
    unsigned short* hB = (unsigned short*)carve((size_t)NP * HD * 2);
    unsigned short* wHi[9];
    unsigned short* wLo[9];
    int wK[9] = {F_IN, HD, HD, HD, HD, HD, HD, HD, HD};
    for (int i = 0; i < 9; i++) {
        wHi[i] = (unsigned short*)carve((size_t)wK[i] * HD * 2);
        wLo[i] = (unsigned short*)carve((size_t)wK[i] * HD * 2);
    }
    (void)ws_size;

    init_zero<<<(GG * HD + 255) / 256, 256, 0, stream>>>(cnt_node, pooled);
    build_graph<<<(EE + 255) / 256, 256, 0, stream>>>(ei, cnt_node, bucket);

    PrepArgs pa;
    for (int l = 0; l < 3; l++)
        for (int s = 0; s < 3; s++) {
            int i = l * 3 + s;
            pa.d[i].src = cw[l][2 * s];
            pa.d[i].dhi = wHi[i];
            pa.d[i].dlo = wLo[i];
            pa.d[i].K = wK[i];
        }
    prep_weights<<<dim3(16, 9), 256, 0, stream>>>(pa);

    const int blocks = NP / 32;   // 4688 blocks x 128 threads (2 waves x 16 nodes)

    // ---- GIN layer 0 (K=32, fp32 in): x -> hA (bf16) ----
    gin_layer<F_IN, false, false><<<blocks, 128, 0, stream>>>(x, cnt_node, bucket,
        wHi[0], wLo[0], cw[0][1], wHi[1], wLo[1], cw[0][3], wHi[2], wLo[2], cw[0][5],
        hA, batch, pooled);
    // ---- GIN layer 1 (bf16 in): hA -> hB (bf16) ----
    gin_layer<HD, true, false><<<blocks, 128, 0, stream>>>(hA, cnt_node, bucket,
        wHi[3], wLo[3], cw[1][1], wHi[4], wLo[4], cw[1][3], wHi[5], wLo[5], cw[1][5],
        hB, batch, pooled);
    // ---- GIN layer 2 (bf16 in): hB -> pooled (fused mean-pool sum) ----
    gin_layer<HD, true, true><<<blocks, 128, 0, stream>>>(hB, cnt_node, bucket,
        wHi[6], wLo[6], cw[2][1], wHi[7], wLo[7], cw[2][3], wHi[8], wLo[8], cw[2][5],
        nullptr, batch, pooled);

    // ---- head ----
    head<<<GG, 128, 0, stream>>>(pooled, batch, fc0_w, fc0_b, fc1_w, fc1_b, out_w, out_b, out);
}

// Round 6
// 459.916 us; speedup vs baseline: 2.2382x; 1.3446x over previous
//
#include <hip/hip_runtime.h>
#include <hip/hip_bf16.h>

// Problem constants (fixed by the reference)
#define NN 150000      // nodes
#define EE 600000      // edges
#define F_IN 32        // input node features
#define HD 128         // hidden dim
#define GG 2048        // graphs
#define CAP 28         // max degree bucket capacity (Poisson(4): P(deg>=28) ~ 4e-18)
#define NP 150016      // NN rounded up to 128-node blocks: 1172*128

typedef __attribute__((ext_vector_type(8))) short bf16x8;
typedef __attribute__((ext_vector_type(4))) float f32x4;

__device__ inline void split_bf16(float v, unsigned short& hi, unsigned short& lo) {
    __hip_bfloat16 h = __float2bfloat16(v);
    float hv = __bfloat162float(h);
    __hip_bfloat16 l = __float2bfloat16(v - hv);
    hi = *reinterpret_cast<unsigned short*>(&h);
    lo = *reinterpret_cast<unsigned short*>(&l);
}
__device__ inline unsigned short bf16_hi(float v) {
    __hip_bfloat16 h = __float2bfloat16(v);
    return *reinterpret_cast<unsigned short*>(&h);
}
__device__ inline float bf2f(unsigned short u) {
    union { unsigned int i; float f; } c;
    c.i = ((unsigned int)u) << 16;
    return c.f;
}

// ---------------------------------------------------------------------------
// Zero-init for workspace regions
// ---------------------------------------------------------------------------
__global__ void init_zero(int* __restrict__ cnt_node, float* __restrict__ pooled) {
    int i = blockIdx.x * blockDim.x + threadIdx.x;
    if (i < NN) cnt_node[i] = 0;
    if (i < GG * HD) pooled[i] = 0.f;
}

// ---------------------------------------------------------------------------
// CSR-bucket build. AoS bucket[dst*CAP+slot].
// ---------------------------------------------------------------------------
__global__ void build_graph(const int* __restrict__ ei,
                            int* __restrict__ cnt_node,
                            int* __restrict__ bucket) {
    int e = blockIdx.x * blockDim.x + threadIdx.x;
    if (e >= EE) return;
    int src = ei[e];         // edge_index[0]
    int dst = ei[EE + e];    // edge_index[1]
    int slot = atomicAdd(&cnt_node[dst], 1);
    if (slot < CAP) bucket[dst * CAP + slot] = src;
}

// ---------------------------------------------------------------------------
// Weight prep: fp32 W[K][H] -> split-bf16 packed in LANE-LINEAR fragment order
// ---------------------------------------------------------------------------
struct PrepDesc { const float* src; unsigned short* dhi; unsigned short* dlo; int K; };
struct PrepArgs { PrepDesc d[9]; };

__global__ void prep_weights(PrepArgs pa) {
    PrepDesc de = pa.d[blockIdx.y];
    int total = de.K * HD;
    int KS = de.K >> 5;
    for (int idx = blockIdx.x * blockDim.x + threadIdx.x; idx < total;
         idx += gridDim.x * blockDim.x) {
        int k = idx / HD, h = idx - (idx / HD) * HD;   // src is [K][H]
        unsigned short hi, lo;
        split_bf16(de.src[idx], hi, lo);
        int nt = h >> 4, m = h & 15;
        int ks = k >> 5, quad = (k >> 3) & 3, e = k & 7;
        int lane = quad * 16 + m;
        int pidx = ((nt * KS + ks) * 64 + lane) * 8 + e;
        de.dhi[pidx] = hi;
        de.dlo[pidx] = lo;
    }
}

// ---------------------------------------------------------------------------
// Fused GIN layer (R6): gather-aggregate + 3-stage MFMA MLP.
//
// R6 THEORY: the ~135us/layer floor is INSTRUCTION-FETCH bound. The old
// kernel was ~40-60 KB of straight-line code (fully unrolled 576 MFMAs +
// transposes) executed ONCE per wave: zero I$ reuse, every wave streams
// the whole body through the 32 KB I-cache at ~L2 latency per line. This
// explains all pipes <20% busy, the gather-free mlp (R2) taking the same
// time, data-side invariance (R5..R15 prior session), and R5's regression
// (2x waves x same code = 2x I-fetch). Fix: roll the nt-loops
// (#pragma unroll 1), fold bias+relu+split+LDS-write into the loop body
// (no acc arrays -> no runtime reg indexing), process s-halves as two
// rolled passes per stage. Code ~10 KB -> I$-resident.
// Geometry reverted to best-known R3/R4: 128 nodes/block, 256 thr, 32 KB
// swizzled LDS, launch_bounds(256,3) (natural VGPR, no spill).
// ---------------------------------------------------------------------------
template <int K_IN, bool BF16IN, bool POOL>
__launch_bounds__(256, 3)
__global__ void gin_layer(const void* __restrict__ hin_,
                          const int* __restrict__ cnt_node,
                          const int* __restrict__ bucket,
                          const unsigned short* __restrict__ w1h, const unsigned short* __restrict__ w1l,
                          const float* __restrict__ b1,
                          const unsigned short* __restrict__ w2h, const unsigned short* __restrict__ w2l,
                          const float* __restrict__ b2,
                          const unsigned short* __restrict__ w3h, const unsigned short* __restrict__ w3l,
                          const float* __restrict__ b3,
                          unsigned short* __restrict__ out,   // bf16 activations (non-pool)
                          const int* __restrict__ batch,
                          float* __restrict__ pooled) {
    constexpr int KS1 = K_IN / 32;
    constexpr int UN = BF16IN ? 4 : (KS1 == 1 ? 8 : 2);   // gather unroll depth
    // Per-wave swizzled transpose buffer: 16 rows x 128 u32 = 8 KB.
    __shared__ unsigned int shp[4][16][128];

    const int wave = threadIdx.x >> 6;
    const int lane = threadIdx.x & 63;
    const int m = lane & 15;      // node row within a 16-set / out-feature col
    const int quad = lane >> 4;   // 0..3
    const int nodeBase = blockIdx.x * 128 + wave * 32;

    const float* hf = (const float*)hin_;
    const unsigned short* hb = (const unsigned short*)hin_;

    // ---- fused aggregation: self + neighbors, fp32 -> split-bf16 A frags ----
    bf16x8 ah[2][KS1], al[2][KS1];
#pragma unroll
    for (int s = 0; s < 2; s++) {
        int node = nodeBase + s * 16 + m;
        node = node < NN ? node : NN - 1;
        float ag[KS1][8];
        if (BF16IN) {
            const unsigned short* rs = hb + (size_t)node * K_IN + quad * 8;
#pragma unroll
            for (int ks = 0; ks < KS1; ks++) {
                bf16x8 v = *(const bf16x8*)(rs + ks * 32);
#pragma unroll
                for (int e = 0; e < 8; e++) ag[ks][e] = bf2f((unsigned short)v[e]);
            }
        } else {
            const float* rs = hf + (size_t)node * K_IN + quad * 8;
#pragma unroll
            for (int ks = 0; ks < KS1; ks++) {
                float4 v0 = *(const float4*)(rs + ks * 32);
                float4 v1 = *(const float4*)(rs + ks * 32 + 4);
                ag[ks][0] = v0.x; ag[ks][1] = v0.y; ag[ks][2] = v0.z; ag[ks][3] = v0.w;
                ag[ks][4] = v1.x; ag[ks][5] = v1.y; ag[ks][6] = v1.z; ag[ks][7] = v1.w;
            }
        }
        int cnt = cnt_node[node];
        cnt = cnt < CAP ? cnt : CAP;
        const int* b = bucket + (size_t)node * CAP;
        int i = 0;
        if (BF16IN) {
            for (; i + UN <= cnt; i += UN) {
                bf16x8 v[UN][KS1];
#pragma unroll
                for (int j = 0; j < UN; j++) {
                    const unsigned short* r = hb + (size_t)b[i + j] * K_IN + quad * 8;
#pragma unroll
                    for (int ks = 0; ks < KS1; ks++)
                        v[j][ks] = *(const bf16x8*)(r + ks * 32);
                }
#pragma unroll
                for (int ks = 0; ks < KS1; ks++)
#pragma unroll
                    for (int e = 0; e < 8; e++) {
                        float t01 = bf2f((unsigned short)v[0][ks][e]) +
                                    bf2f((unsigned short)v[1][ks][e]);
                        float t23 = bf2f((unsigned short)v[2][ks][e]) +
                                    bf2f((unsigned short)v[3][ks][e]);
                        ag[ks][e] += t01 + t23;
                    }
            }
            for (; i < cnt; i++) {
                const unsigned short* r = hb + (size_t)b[i] * K_IN + quad * 8;
#pragma unroll
                for (int ks = 0; ks < KS1; ks++) {
                    bf16x8 v = *(const bf16x8*)(r + ks * 32);
#pragma unroll
                    for (int e = 0; e < 8; e++) ag[ks][e] += bf2f((unsigned short)v[e]);
                }
            }
        } else {
            for (; i + UN <= cnt; i += UN) {
                float4 v0[UN][KS1], v1[UN][KS1];
#pragma unroll
                for (int j = 0; j < UN; j++) {
                    const float* r = hf + (size_t)b[i + j] * K_IN + quad * 8;
#pragma unroll
                    for (int ks = 0; ks < KS1; ks++) {
                        v0[j][ks] = *(const float4*)(r + ks * 32);
                        v1[j][ks] = *(const float4*)(r + ks * 32 + 4);
                    }
                }
#pragma unroll
                for (int ks = 0; ks < KS1; ks++) {
#pragma unroll
                    for (int e = 0; e < 4; e++) {
                        float s01 = (&v0[0][ks].x)[e] + (&v0[1][ks].x)[e];
                        float s23 = (&v0[2][ks].x)[e] + (&v0[3][ks].x)[e];
                        if (UN == 8) {
                            s01 += (&v0[4][ks].x)[e] + (&v0[5][ks].x)[e];
                            s23 += (&v0[6][ks].x)[e] + (&v0[7][ks].x)[e];
                        }
                        ag[ks][e] += s01 + s23;
                    }
#pragma unroll
                    for (int e = 0; e < 4; e++) {
                        float s01 = (&v1[0][ks].x)[e] + (&v1[1][ks].x)[e];
                        float s23 = (&v1[2][ks].x)[e] + (&v1[3][ks].x)[e];
                        if (UN == 8) {
                            s01 += (&v1[4][ks].x)[e] + (&v1[5][ks].x)[e];
                            s23 += (&v1[6][ks].x)[e] + (&v1[7][ks].x)[e];
                        }
                        ag[ks][e + 4] += s01 + s23;
                    }
                }
            }
            for (; i < cnt; i++) {
                const float* r = hf + (size_t)b[i] * K_IN + quad * 8;
#pragma unroll
                for (int ks = 0; ks < KS1; ks++) {
                    float4 v0 = *(const float4*)(r + ks * 32);
                    float4 v1 = *(const float4*)(r + ks * 32 + 4);
                    ag[ks][0] += v0.x; ag[ks][1] += v0.y; ag[ks][2] += v0.z; ag[ks][3] += v0.w;
                    ag[ks][4] += v1.x; ag[ks][5] += v1.y; ag[ks][6] += v1.z; ag[ks][7] += v1.w;
                }
            }
        }
#pragma unroll
        for (int ks = 0; ks < KS1; ks++) {
            bf16x8 vh, vl;
#pragma unroll
            for (int e = 0; e < 8; e++) {
                unsigned short hi, lo;
                split_bf16(ag[ks][e], hi, lo);
                vh[e] = (short)hi;
                vl[e] = (short)lo;
            }
            ah[s][ks] = vh;
            al[s][ks] = vl;
        }
    }

    bf16x8 a2h[2][4], a2l[2][4];
    const int fxm = (m & 7) << 2;          // read-side swizzle for row m

    // ---- stage 1: per s-half, ROLLED nt loop, immediate transpose write ----
#pragma unroll
    for (int s = 0; s < 2; s++) {
#pragma unroll 1
        for (int nt = 0; nt < 8; nt++) {
            f32x4 c = {0.f, 0.f, 0.f, 0.f};
#pragma unroll
            for (int ks = 0; ks < KS1; ks++) {
                bf16x8 bh = *(const bf16x8*)(w1h + ((nt * KS1 + ks) * 64 + lane) * 8);
                bf16x8 bl = *(const bf16x8*)(w1l + ((nt * KS1 + ks) * 64 + lane) * 8);
                c = __builtin_amdgcn_mfma_f32_16x16x32_bf16(ah[s][ks], bh, c, 0, 0, 0);
                c = __builtin_amdgcn_mfma_f32_16x16x32_bf16(al[s][ks], bh, c, 0, 0, 0);
                c = __builtin_amdgcn_mfma_f32_16x16x32_bf16(ah[s][ks], bl, c, 0, 0, 0);
            }
            float bj = b1[nt * 16 + m];
#pragma unroll
            for (int r = 0; r < 4; r++) {
                unsigned short hi, lo;
                split_bf16(fmaxf(c[r] + bj, 0.f), hi, lo);
                int row = quad * 4 + r;
                shp[wave][row][(nt * 16 + m) ^ ((row & 7) << 2)] =
                    (unsigned int)hi | ((unsigned int)lo << 16);
            }
        }
#pragma unroll
        for (int ks = 0; ks < 4; ks++) {
            const unsigned int* rowp = &shp[wave][m][0];
            int base = ks * 32 + quad * 8;
            uint4 wa = *(const uint4*)&rowp[base ^ fxm];
            uint4 wb = *(const uint4*)&rowp[(base + 4) ^ fxm];
            union { unsigned int u[4]; bf16x8 v; } ch, cl;
            ch.u[0] = __builtin_amdgcn_perm(wa.y, wa.x, 0x05040100u);
            ch.u[1] = __builtin_amdgcn_perm(wa.w, wa.z, 0x05040100u);
            ch.u[2] = __builtin_amdgcn_perm(wb.y, wb.x, 0x05040100u);
            ch.u[3] = __builtin_amdgcn_perm(wb.w, wb.z, 0x05040100u);
            cl.u[0] = __builtin_amdgcn_perm(wa.y, wa.x, 0x07060302u);
            cl.u[1] = __builtin_amdgcn_perm(wa.w, wa.z, 0x07060302u);
            cl.u[2] = __builtin_amdgcn_perm(wb.y, wb.x, 0x07060302u);
            cl.u[3] = __builtin_amdgcn_perm(wb.w, wb.z, 0x07060302u);
            a2h[s][ks] = ch.v;
            a2l[s][ks] = cl.v;
        }
    }

    // ---- stage 2: per s-half, rolled nt; results overwrite a2h/a2l[s] ----
#pragma unroll
    for (int s = 0; s < 2; s++) {
#pragma unroll 1
        for (int nt = 0; nt < 8; nt++) {
            f32x4 c = {0.f, 0.f, 0.f, 0.f};
#pragma unroll
            for (int ks = 0; ks < 4; ks++) {
                bf16x8 bh = *(const bf16x8*)(w2h + ((nt * 4 + ks) * 64 + lane) * 8);
                bf16x8 bl = *(const bf16x8*)(w2l + ((nt * 4 + ks) * 64 + lane) * 8);
                c = __builtin_amdgcn_mfma_f32_16x16x32_bf16(a2h[s][ks], bh, c, 0, 0, 0);
                c = __builtin_amdgcn_mfma_f32_16x16x32_bf16(a2l[s][ks], bh, c, 0, 0, 0);
                c = __builtin_amdgcn_mfma_f32_16x16x32_bf16(a2h[s][ks], bl, c, 0, 0, 0);
            }
            float bj = b2[nt * 16 + m];
#pragma unroll
            for (int r = 0; r < 4; r++) {
                unsigned short hi, lo;
                split_bf16(fmaxf(c[r] + bj, 0.f), hi, lo);
                int row = quad * 4 + r;
                shp[wave][row][(nt * 16 + m) ^ ((row & 7) << 2)] =
                    (unsigned int)hi | ((unsigned int)lo << 16);
            }
        }
#pragma unroll
        for (int ks = 0; ks < 4; ks++) {
            const unsigned int* rowp = &shp[wave][m][0];
            int base = ks * 32 + quad * 8;
            uint4 wa = *(const uint4*)&rowp[base ^ fxm];
            uint4 wb = *(const uint4*)&rowp[(base + 4) ^ fxm];
            union { unsigned int u[4]; bf16x8 v; } ch, cl;
            ch.u[0] = __builtin_amdgcn_perm(wa.y, wa.x, 0x05040100u);
            ch.u[1] = __builtin_amdgcn_perm(wa.w, wa.z, 0x05040100u);
            ch.u[2] = __builtin_amdgcn_perm(wb.y, wb.x, 0x05040100u);
            ch.u[3] = __builtin_amdgcn_perm(wb.w, wb.z, 0x05040100u);
            cl.u[0] = __builtin_amdgcn_perm(wa.y, wa.x, 0x07060302u);
            cl.u[1] = __builtin_amdgcn_perm(wa.w, wa.z, 0x07060302u);
            cl.u[2] = __builtin_amdgcn_perm(wb.y, wb.x, 0x07060302u);
            cl.u[3] = __builtin_amdgcn_perm(wb.w, wb.z, 0x07060302u);
            a2h[s][ks] = ch.v;   // stage-2 inputs for this s are dead: reuse
            a2l[s][ks] = cl.v;
        }
    }

    // ---- stage 3: per s-half, rolled nt, epilogue folded into the loop ----
    if (POOL) {
        float* shf = (float*)&shp[wave][0][0];
#pragma unroll
        for (int h = 0; h < 2; h++) {
#pragma unroll 1
            for (int nt = 0; nt < 8; nt++) {
                f32x4 c = {0.f, 0.f, 0.f, 0.f};
#pragma unroll
                for (int ks = 0; ks < 4; ks++) {
                    bf16x8 bh = *(const bf16x8*)(w3h + ((nt * 4 + ks) * 64 + lane) * 8);
                    bf16x8 bl = *(const bf16x8*)(w3l + ((nt * 4 + ks) * 64 + lane) * 8);
                    c = __builtin_amdgcn_mfma_f32_16x16x32_bf16(a2h[h][ks], bh, c, 0, 0, 0);
                    c = __builtin_amdgcn_mfma_f32_16x16x32_bf16(a2l[h][ks], bh, c, 0, 0, 0);
                    c = __builtin_amdgcn_mfma_f32_16x16x32_bf16(a2h[h][ks], bl, c, 0, 0, 0);
                }
                float bj = b3[nt * 16 + m];
#pragma unroll
                for (int r = 0; r < 4; r++) {
                    int row = quad * 4 + r;
                    shf[row * 128 + ((nt * 16 + m) ^ ((row & 7) << 2))] =
                        fmaxf(c[r] + bj, 0.f);
                }
            }
            int c0 = lane * 2;
            float run0 = 0.f, run1 = 0.f;
            int gp = -1;
            for (int rrow = 0; rrow < 16; rrow++) {
                int node = nodeBase + h * 16 + rrow;
                if (node >= NN) break;
                int g = batch[node];
                float2 xv = *(const float2*)&shf[rrow * 128 + (c0 ^ ((rrow & 7) << 2))];
                if (g != gp) {
                    if (gp >= 0) {
                        atomicAdd(&pooled[(size_t)gp * HD + c0 + 0], run0);
                        atomicAdd(&pooled[(size_t)gp * HD + c0 + 1], run1);
                    }
                    run0 = xv.x; run1 = xv.y; gp = g;
                } else {
                    run0 += xv.x; run1 += xv.y;
                }
            }
            if (gp >= 0) {
                atomicAdd(&pooled[(size_t)gp * HD + c0 + 0], run0);
                atomicAdd(&pooled[(size_t)gp * HD + c0 + 1], run1);
            }
        }
    } else {
        unsigned short* sh16 = (unsigned short*)&shp[wave][0][0];  // [16][256] hw
#pragma unroll
        for (int s = 0; s < 2; s++) {
#pragma unroll 1
            for (int nt = 0; nt < 8; nt++) {
                f32x4 c = {0.f, 0.f, 0.f, 0.f};
#pragma unroll
                for (int ks = 0; ks < 4; ks++) {
                    bf16x8 bh = *(const bf16x8*)(w3h + ((nt * 4 + ks) * 64 + lane) * 8);
                    bf16x8 bl = *(const bf16x8*)(w3l + ((nt * 4 + ks) * 64 + lane) * 8);
                    c = __builtin_amdgcn_mfma_f32_16x16x32_bf16(a2h[s][ks], bh, c, 0, 0, 0);
                    c = __builtin_amdgcn_mfma_f32_16x16x32_bf16(a2l[s][ks], bh, c, 0, 0, 0);
                    c = __builtin_amdgcn_mfma_f32_16x16x32_bf16(a2h[s][ks], bl, c, 0, 0, 0);
                }
                float bj = b3[nt * 16 + m];
#pragma unroll
                for (int r = 0; r < 4; r++) {
                    int row = quad * 4 + r;
                    int hh = nt * 16 + m;                  // feature halfword idx
                    int w2 = (hh >> 1) ^ ((row & 7) << 2); // swizzled word
                    sh16[row * 256 + w2 * 2 + (hh & 1)] =
                        bf16_hi(fmaxf(c[r] + bj, 0.f));
                }
            }
#pragma unroll
            for (int io = 0; io < 4; io++) {
                int row16 = io * 4 + quad;
                int wbase = (m * 4) ^ ((row16 & 7) << 2);
                int n2 = nodeBase + s * 16 + row16;
                bf16x8 v = *(const bf16x8*)&sh16[row16 * 256 + wbase * 2];
                if (n2 < NN) *(bf16x8*)&out[(size_t)n2 * HD + m * 8] = v;
            }
        }
    }
}

// ---------------------------------------------------------------------------
// Classifier head: one block (128 threads) per graph.
// Graph node counts via binary search on the SORTED batch array.
// ---------------------------------------------------------------------------
__device__ inline int lb_batch(const int* __restrict__ batch, int key) {
    int lo = 0, hi = NN;
    while (lo < hi) {
        int mid = (lo + hi) >> 1;
        if (batch[mid] < key) lo = mid + 1; else hi = mid;
    }
    return lo;
}

__launch_bounds__(128)
__global__ void head(const float* __restrict__ pooled, const int* __restrict__ batch,
                     const float* __restrict__ fc0_w, const float* __restrict__ fc0_b,
                     const float* __restrict__ fc1_w, const float* __restrict__ fc1_b,
                     const float* __restrict__ out_w, const float* __restrict__ out_b,
                     float* __restrict__ out) {
    int g = blockIdx.x;
    int j = threadIdx.x;
    __shared__ float s0[HD];
    __shared__ float s1[HD];
    int c = lb_batch(batch, g + 1) - lb_batch(batch, g);
    float cf = (float)(c > 1 ? c : 1);
    s0[j] = pooled[(size_t)g * HD + j] / cf;
    __syncthreads();

    float acc = fc0_b[j];
    for (int k = 0; k < HD; k += 4) {
        float4 hv = *(const float4*)&s0[k];
        acc = fmaf(hv.x, fc0_w[(k + 0) * HD + j], acc);
        acc = fmaf(hv.y, fc0_w[(k + 1) * HD + j], acc);
        acc = fmaf(hv.z, fc0_w[(k + 2) * HD + j], acc);
        acc = fmaf(hv.w, fc0_w[(k + 3) * HD + j], acc);
    }
    s1[j] = fmaxf(acc, 0.0f);
    __syncthreads();

    acc = fc1_b[j];
    for (int k = 0; k < HD; k += 4) {
        float4 hv = *(const float4*)&s1[k];
        acc = fmaf(hv.x, fc1_w[(k + 0) * HD + j], acc);
        acc = fmaf(hv.y, fc1_w[(k + 1) * HD + j], acc);
        acc = fmaf(hv.z, fc1_w[(k + 2) * HD + j], acc);
        acc = fmaf(hv.w, fc1_w[(k + 3) * HD + j], acc);
    }
    float v = fmaxf(acc, 0.0f);

    float p0 = v * out_w[j * 2 + 0];
    float p1 = v * out_w[j * 2 + 1];
    __syncthreads();
    s0[j] = p0;
    s1[j] = p1;
    __syncthreads();
    for (int off = 64; off >= 1; off >>= 1) {
        if (j < off) {
            s0[j] += s0[j + off];
            s1[j] += s1[j + off];
        }
        __syncthreads();
    }
    if (j == 0) {
        out[(size_t)g * 2 + 0] = s0[0] + out_b[0];
        out[(size_t)g * 2 + 1] = s1[0] + out_b[1];
    }
}

// ---------------------------------------------------------------------------
extern "C" void kernel_launch(void* const* d_in, const int* in_sizes, int n_in,
                              void* d_out, int out_size, void* d_ws, size_t ws_size,
                              hipStream_t stream) {
    const float* x     = (const float*)d_in[0];
    const int*   ei    = (const int*)d_in[1];
    const int*   batch = (const int*)d_in[2];
    const float* cw[3][6];
    for (int i = 0; i < 3; i++)
        for (int k = 0; k < 6; k++) cw[i][k] = (const float*)d_in[3 + 6 * i + k];
    const float* fc0_w = (const float*)d_in[21];
    const float* fc0_b = (const float*)d_in[22];
    const float* fc1_w = (const float*)d_in[23];
    const float* fc1_b = (const float*)d_in[24];
    const float* out_w = (const float*)d_in[25];
    const float* out_b = (const float*)d_in[26];
    float* out = (float*)d_out;

    char* ws = (char*)d_ws;
    size_t off = 0;
    auto carve = [&](size_t bytes) {
        void* p = ws + off;
        off += (bytes + 255) & ~(size_t)255;
        return p;
    };
    // cnt_node and pooled contiguous (zeroed together by init_zero)
    int*   cnt_node = (int*)carve((size_t)NN * 4);
    float* pooled   = (float*)carve((size_t)GG * HD * 4);
    int*   bucket   = (int*)carve((size_t)NN * CAP * 4);
    unsigned short* hA = (unsigned short*)carve((size_t)NP * HD * 2);
    unsigned short* hB = (unsigned short*)carve((size_t)NP * HD * 2);
    unsigned short* wHi[9];
    unsigned short* wLo[9];
    int wK[9] = {F_IN, HD, HD, HD, HD, HD, HD, HD, HD};
    for (int i = 0; i < 9; i++) {
        wHi[i] = (unsigned short*)carve((size_t)wK[i] * HD * 2);
        wLo[i] = (unsigned short*)carve((size_t)wK[i] * HD * 2);
    }
    (void)ws_size;

    init_zero<<<(GG * HD + 255) / 256, 256, 0, stream>>>(cnt_node, pooled);
    build_graph<<<(EE + 255) / 256, 256, 0, stream>>>(ei, cnt_node, bucket);

    PrepArgs pa;
    for (int l = 0; l < 3; l++)
        for (int s = 0; s < 3; s++) {
            int i = l * 3 + s;
            pa.d[i].src = cw[l][2 * s];
            pa.d[i].dhi = wHi[i];
            pa.d[i].dlo = wLo[i];
            pa.d[i].K = wK[i];
        }
    prep_weights<<<dim3(16, 9), 256, 0, stream>>>(pa);

    const int blocks = NP / 128;  // 1172

    // ---- GIN layer 0 (K=32, fp32 in): x -> hA (bf16) ----
    gin_layer<F_IN, false, false><<<blocks, 256, 0, stream>>>(x, cnt_node, bucket,
        wHi[0], wLo[0], cw[0][1], wHi[1], wLo[1], cw[0][3], wHi[2], wLo[2], cw[0][5],
        hA, batch, pooled);
    // ---- GIN layer 1 (bf16 in): hA -> hB (bf16) ----
    gin_layer<HD, true, false><<<blocks, 256, 0, stream>>>(hA, cnt_node, bucket,
        wHi[3], wLo[3], cw[1][1], wHi[4], wLo[4], cw[1][3], wHi[5], wLo[5], cw[1][5],
        hB, batch, pooled);
    // ---- GIN layer 2 (bf16 in): hB -> pooled (fused mean-pool sum) ----
    gin_layer<HD, true, true><<<blocks, 256, 0, stream>>>(hB, cnt_node, bucket,
        wHi[6], wLo[6], cw[2][1], wHi[7], wLo[7], cw[2][3], wHi[8], wLo[8], cw[2][5],
        nullptr, batch, pooled);

    // ---- head ----
    head<<<GG, 128, 0, stream>>>(pooled, batch, fc0_w, fc0_b, fc1_w, fc1_b, out_w, out_b, out);
}